// Round 1
// baseline (838.517 us; speedup 1.0000x reference)
//
#include <hip/hip_runtime.h>

#define NPAR 8384
#define NBATCH 8192

typedef __attribute__((ext_vector_type(8))) short    sh8;
typedef __attribute__((ext_vector_type(8))) __bf16   bf8_t;
typedef __attribute__((ext_vector_type(4))) float    f4;

__device__ __forceinline__ unsigned short f2bf(float v){
  unsigned int u = __float_as_uint(v);
  u = u + 0x7FFFu + ((u >> 16) & 1u);          // RNE to bf16
  return (unsigned short)(u >> 16);
}
__device__ __forceinline__ float bf2f(unsigned short b){
  return __uint_as_float(((unsigned int)b) << 16);
}

// One workgroup per batch item n.
// LDS: L (post-transform) as bf16 hi/lo pair, 128x128 each, slot-XOR swizzled:
//   element (r, j) lives at ushort index (r<<7) + ((jb ^ (r&7))<<3) + (j&7),  jb = j>>3
// Phase 1: build L into LDS. Phase 2 (wave 0): sample + kl. Phase 3: Sigma via
// bf16-split MFMA (HH + HL + LH), quadrant-partitioned across the 4 waves with
// triangular K-skipping; heavy BR quadrant rotated by n across waves 1..3.
__global__ __launch_bounds__(256, 2)
void flk_kernel(const float* __restrict__ P, const float* __restrict__ E,
                float* __restrict__ out)
{
  __shared__ unsigned short Lhi[128*128];   // 32 KB
  __shared__ unsigned short Llo[128*128];   // 32 KB  (total exactly 64 KB)
  const int n   = blockIdx.x;
  const int tid = threadIdx.x;
  const float* p = P + (size_t)n * NPAR;

  // ---------------- Phase 1: unpack/transform L into LDS ----------------
  {
    const int r0  = tid >> 2;          // rows r0 and r0+64
    const int jb0 = (tid & 3) << 2;    // 4 slots of 8 elements each per row
#pragma unroll
    for (int h = 0; h < 2; ++h){
      const int r    = r0 + (h << 6);
      const float rinv = 1.0f / sqrtf((float)(r + 1));
      const int rx   = r & 7;
#pragma unroll
      for (int s = 0; s < 4; ++s){
        const int jb = jb0 + s;
        const int j0 = jb << 3;
        float raw[8] = {0,0,0,0,0,0,0,0};
        if (r >= 64){
          // L[r][j] = p[16511 - 128r - j]  (reversed segment) — always in-bounds
          const int base = 16511 - (r << 7);
          float4 a = *(const float4*)(p + base - j0 - 3);
          float4 b = *(const float4*)(p + base - j0 - 7);
          raw[0] = a.w; raw[1] = a.z; raw[2] = a.y; raw[3] = a.x;
          raw[4] = b.w; raw[5] = b.z; raw[6] = b.y; raw[7] = b.x;
        } else {
          // L[r][j] = p[256 + 128r + j]; guard tail (would run past row/array)
          const int basef = 256 + (r << 7) + j0;
          if (j0 + 7 <= r){
            float4 a = *(const float4*)(p + basef);
            float4 b = *(const float4*)(p + basef + 4);
            raw[0]=a.x; raw[1]=a.y; raw[2]=a.z; raw[3]=a.w;
            raw[4]=b.x; raw[5]=b.y; raw[6]=b.z; raw[7]=b.w;
          } else if (j0 <= r){
#pragma unroll
            for (int u = 0; u < 8; ++u)
              if (j0 + u <= r) raw[u] = p[basef + u];
          }
        }
        sh8 vh, vl;
#pragma unroll
        for (int u = 0; u < 8; ++u){
          const int j = j0 + u;
          float v;
          if (j > r)       v = 0.0f;            // strict upper = 0
          else if (j == r) v = expf(raw[u]);    // diag: exp of raw (NOT scaled)
          else             v = raw[u] * rinv;   // scaled by 1/sqrt(r+1)
          const unsigned short hb = f2bf(v);
          vh[u] = (short)hb;
          vl[u] = (short)f2bf(v - bf2f(hb));
        }
        const int idx = (r << 7) + ((jb ^ rx) << 3);
        *(sh8*)&Lhi[idx] = vh;
        *(sh8*)&Llo[idx] = vl;
      }
    }
  }
  __syncthreads();

  // ---------------- Phase 2 (wave 0 only): sample + kl ----------------
  if (tid < 64){
    const int l = tid;
    const float e0 = E[(size_t)n * 128 + l];
    const float e1 = E[(size_t)n * 128 + 64 + l];
    float klp = 0.0f;
#pragma unroll
    for (int h = 0; h < 2; ++h){
      const int r  = l + (h << 6);
      const int rx = r & 7;
      float sacc = 0.0f, dacc = 0.0f;
#pragma unroll
      for (int jb = 0; jb < 16; ++jb){
        const int idx = (r << 7) + ((jb ^ rx) << 3);
        sh8 vh = *(const sh8*)&Lhi[idx];
        sh8 vl = *(const sh8*)&Llo[idx];
#pragma unroll
        for (int u = 0; u < 8; ++u){
          const int j  = (jb << 3) + u;
          const float v = bf2f((unsigned short)vh[u]) + bf2f((unsigned short)vl[u]);
          const float e = (j < 64) ? __shfl(e0, j) : __shfl(e1, j - 64);
          sacc = fmaf(v, e, sacc);
          dacc = fmaf(v, v, dacc);
        }
      }
      const float mean = p[r];
      const float logd = (r < 64) ? p[256 + 129 * r] : p[16511 - 129 * r];
      out[(size_t)n * 128 + r] = mean + sacc;
      klp += dacc - 1.0f + mean * mean - 2.0f * logd;
    }
#pragma unroll
    for (int off = 32; off > 0; off >>= 1) klp += __shfl_down(klp, off);
    if (l == 0) out[(size_t)NBATCH * 128 + n] = 0.5f * klp;
  }

  // ---------------- Phase 3: Sigma = L * L^T via bf16-split MFMA ----------------
  {
    const int w = tid >> 6;
    const int l = tid & 63;
    const int m = l & 15;        // MFMA row/col within 16
    const int g = l >> 4;        // k-group (k-run = g*8)
    // quad 0 (TL) always on wave 0 (it also ran phase 2); rotate 1..3 by n
    const int quad = (w == 0) ? 0 : (1 + (w - 1 + n) % 3);
    const int qr = quad >> 1, qc = quad & 1;
    const int ksteps = (quad == 3) ? 4 : 2;   // TL/TR/BL only need j < 64
    float* sig = out + (size_t)NBATCH * 128 + NBATCH + (size_t)n * 16384;

    f4 acc[4][4];
    {
      f4 zz = {0.0f, 0.0f, 0.0f, 0.0f};
#pragma unroll
      for (int a = 0; a < 4; ++a)
#pragma unroll
        for (int b = 0; b < 4; ++b) acc[a][b] = zz;
    }

    for (int kt = 0; kt < ksteps; ++kt){
      const int jb = (kt << 2) + g;
      sh8 Ah[4], Al[4], Bh[4], Bl[4];
#pragma unroll
      for (int a = 0; a < 4; ++a){
        const int ra = (qr << 6) + (a << 4) + m;
        const int ia = (ra << 7) + ((jb ^ (ra & 7)) << 3);
        Ah[a] = *(const sh8*)&Lhi[ia];
        Al[a] = *(const sh8*)&Llo[ia];
        const int rb = (qc << 6) + (a << 4) + m;
        const int ib = (rb << 7) + ((jb ^ (rb & 7)) << 3);
        Bh[a] = *(const sh8*)&Lhi[ib];
        Bl[a] = *(const sh8*)&Llo[ib];
      }
#pragma unroll
      for (int a = 0; a < 4; ++a){
#pragma unroll
        for (int b = 0; b < 4; ++b){
          const int mn = min((qr << 2) + a, (qc << 2) + b);
          if ((kt << 1) <= mn){   // K-step needed iff 32*kt <= 16*mn+15
            acc[a][b] = __builtin_amdgcn_mfma_f32_16x16x32_bf16(
                __builtin_bit_cast(bf8_t, Ah[a]), __builtin_bit_cast(bf8_t, Bh[b]), acc[a][b], 0, 0, 0);
            acc[a][b] = __builtin_amdgcn_mfma_f32_16x16x32_bf16(
                __builtin_bit_cast(bf8_t, Ah[a]), __builtin_bit_cast(bf8_t, Bl[b]), acc[a][b], 0, 0, 0);
            acc[a][b] = __builtin_amdgcn_mfma_f32_16x16x32_bf16(
                __builtin_bit_cast(bf8_t, Al[a]), __builtin_bit_cast(bf8_t, Bh[b]), acc[a][b], 0, 0, 0);
          }
        }
      }
    }
    // C/D layout: col = lane&15, row = (lane>>4)*4 + reg  (Sigma symmetric, so
    // even a transposed mapping would still be numerically correct)
#pragma unroll
    for (int a = 0; a < 4; ++a){
      const int row0 = (qr << 6) + (a << 4) + (g << 2);
#pragma unroll
      for (int b = 0; b < 4; ++b){
        const int col = (qc << 6) + (b << 4) + m;
#pragma unroll
        for (int q = 0; q < 4; ++q){
          sig[(size_t)(row0 + q) * 128 + col] = acc[a][b][q];
        }
      }
    }
  }
}

extern "C" void kernel_launch(void* const* d_in, const int* in_sizes, int n_in,
                              void* d_out, int out_size, void* d_ws, size_t ws_size,
                              hipStream_t stream)
{
  const float* P  = (const float*)d_in[0];   // (8192, 8384) fp32
  const float* E  = (const float*)d_in[1];   // (8192, 128, 1) fp32
  float* out = (float*)d_out;                // sample | kl | Sigma, flat fp32
  hipLaunchKernelGGL(flk_kernel, dim3(NBATCH), dim3(256), 0, stream, P, E, out);
}